// Round 13
// baseline (11102.221 us; speedup 1.0000x reference)
//
#include <hip/hip_runtime.h>

// Echo State Network, T=1024 sequential steps of r' = 0.5 r + 0.5 tanh(W r + Win u).
// Persistent kernel. W pinned in hard-named AGPRs (verified r4: VGPR_Count=128).
//
// r13 = r11 payload path + SINGLE-COUNTER notification barrier.
// Diagnosis: r5/r11's 128 pollers/WG x 256 WGs = 32K uncached loads/round over
// 8 hot lines (~1.7us/round of line-serialized traffic) congested the very
// lines the flag stores must land on. Fix: one monotonic uint counter.
//  * producers: barrier B (vmcnt drain) -> tid0 atomicAdd(cnt,1) (fire-and-
//    forget; 256 pipelined RMWs on one line).
//  * consumers: every wave polls ONE address (64 lanes same addr = 1 coalesced
//    transaction/wave/round; 2048 device-wide vs 32K). cnt >= 256*t proves all
//    WGs finished step t-1 (each add is post-drain, post-barrier-A of t-1) =>
//    staging + ping-pong overwrite both safe. Monotonic => no ABA; 4-byte
//    memset node per launch.
//  * no post-poll barrier (each wave self-certifies before staging its own
//    r_lds region; barrier A still gates matvec).
//  * rotated pred kept in the post-add shadow (r11); its r_lds reads are
//    protected by a WORKGROUP-UNIFORM conditional __syncthreads at that WG's
//    next staging (condition is wid/t-only => legal).
// Dead ends (do not revisit): poll-the-data (r6 8ms, r12 7.3ms), all-thread
// flag poll (r7 6ms), acquire fences (r8 19ms), per-wave certificates (r9).
//
// RACE DETECTOR: absmax must read exactly 6.103516e-05. Anything else => race.
//
// d_ws layout: [0, 32768): float rbuf[2][4096] (double-buffered r, 8B-paired)
//              [32768, 32772): uint cnt (monotonic barrier counter)

#define T_STEPS 1024
#define R_DIM   4096
#define N_WG    256
#define N_THR   512
#define ROWS_PER_WG 16
#define K_CHUNKS 16          // R_DIM / (64 lanes * 4 floats)

#define AGENT __HIP_MEMORY_SCOPE_AGENT

typedef unsigned long long ull;
typedef unsigned int uint32;

__device__ __forceinline__ float fast_tanh(float x) {
    float ax = fabsf(x);
    float e  = __expf(-2.0f * ax);
    float t  = (1.0f - e) / (1.0f + e);
    return copysignf(t, x);
}

// Store one float4 into four named physical AGPRs.
#define WST4(A0, A1, A2, A3, vec)                                              \
    asm volatile("v_accvgpr_write_b32 a" #A0 ", %0\n\t"                        \
                 "v_accvgpr_write_b32 a" #A1 ", %1\n\t"                        \
                 "v_accvgpr_write_b32 a" #A2 ", %2\n\t"                        \
                 "v_accvgpr_write_b32 a" #A3 ", %3"                            \
                 :: "v"((vec).x), "v"((vec).y), "v"((vec).z), "v"((vec).w)     \
                 : "a" #A0, "a" #A1, "a" #A2, "a" #A3)

// One K-chunk of the two-row matvec: read 4+4 W values from AGPRs, FMA with rv.
#define MV2(c, A0, A1, A2, A3, B0, B1, B2, B3)                                 \
    do {                                                                       \
        float4 rv = rv4[(c) * 64 + lane];                                      \
        float w0, w1, w2, w3, u0, u1, u2, u3;                                  \
        asm volatile("v_accvgpr_read_b32 %0, a" #A0 "\n\t"                     \
                     "v_accvgpr_read_b32 %1, a" #A1 "\n\t"                     \
                     "v_accvgpr_read_b32 %2, a" #A2 "\n\t"                     \
                     "v_accvgpr_read_b32 %3, a" #A3 "\n\t"                     \
                     "v_accvgpr_read_b32 %4, a" #B0 "\n\t"                     \
                     "v_accvgpr_read_b32 %5, a" #B1 "\n\t"                     \
                     "v_accvgpr_read_b32 %6, a" #B2 "\n\t"                     \
                     "v_accvgpr_read_b32 %7, a" #B3                            \
                     : "=v"(w0), "=v"(w1), "=v"(w2), "=v"(w3),                 \
                       "=v"(u0), "=v"(u1), "=v"(u2), "=v"(u3));                \
        accA.x = fmaf(w0, rv.x, accA.x);                                       \
        accA.y = fmaf(w1, rv.y, accA.y);                                       \
        accA.z = fmaf(w2, rv.z, accA.z);                                       \
        accA.w = fmaf(w3, rv.w, accA.w);                                       \
        accB.x = fmaf(u0, rv.x, accB.x);                                       \
        accB.y = fmaf(u1, rv.y, accB.y);                                       \
        accB.z = fmaf(u2, rv.z, accB.z);                                       \
        accB.w = fmaf(u3, rv.w, accB.w);                                       \
    } while (0)

__global__ __launch_bounds__(N_THR, 2)
void esn_persistent(const float* __restrict__ batch,
                    const float* __restrict__ Win,
                    const float* __restrict__ W,
                    const float* __restrict__ Wout,
                    float* __restrict__ out,
                    float* __restrict__ rbuf,
                    uint32* __restrict__ cnt)
{
    __shared__ __align__(16) float r_lds[R_DIM];   // current r(t)
    __shared__ float b_lds[T_STEPS];               // input sequence

    const int tid  = threadIdx.x;
    const int wid  = blockIdx.x;
    const int wave = tid >> 6;
    const int lane = tid & 63;
    const int rowA = wid * ROWS_PER_WG + wave * 2; // this wave's two W rows
    const int rowB = rowA + 1;

    for (int i = tid; i < R_DIM; i += N_THR) r_lds[i] = 0.0f;   // r(0) = 0
    for (int i = tid; i < T_STEPS; i += N_THR) b_lds[i] = batch[i];

    // Pin W rows in physical AGPRs. Lane's chunk c covers k = c*256 + lane*4.
    {
        const float4* pA = reinterpret_cast<const float4*>(W + (size_t)rowA * R_DIM);
        const float4* pB = reinterpret_cast<const float4*>(W + (size_t)rowB * R_DIM);
        float4 v;
        v = pA[ 0 * 64 + lane]; WST4(  0,   1,   2,   3, v);
        v = pA[ 1 * 64 + lane]; WST4(  4,   5,   6,   7, v);
        v = pA[ 2 * 64 + lane]; WST4(  8,   9,  10,  11, v);
        v = pA[ 3 * 64 + lane]; WST4( 12,  13,  14,  15, v);
        v = pA[ 4 * 64 + lane]; WST4( 16,  17,  18,  19, v);
        v = pA[ 5 * 64 + lane]; WST4( 20,  21,  22,  23, v);
        v = pA[ 6 * 64 + lane]; WST4( 24,  25,  26,  27, v);
        v = pA[ 7 * 64 + lane]; WST4( 28,  29,  30,  31, v);
        v = pA[ 8 * 64 + lane]; WST4( 32,  33,  34,  35, v);
        v = pA[ 9 * 64 + lane]; WST4( 36,  37,  38,  39, v);
        v = pA[10 * 64 + lane]; WST4( 40,  41,  42,  43, v);
        v = pA[11 * 64 + lane]; WST4( 44,  45,  46,  47, v);
        v = pA[12 * 64 + lane]; WST4( 48,  49,  50,  51, v);
        v = pA[13 * 64 + lane]; WST4( 52,  53,  54,  55, v);
        v = pA[14 * 64 + lane]; WST4( 56,  57,  58,  59, v);
        v = pA[15 * 64 + lane]; WST4( 60,  61,  62,  63, v);
        v = pB[ 0 * 64 + lane]; WST4( 64,  65,  66,  67, v);
        v = pB[ 1 * 64 + lane]; WST4( 68,  69,  70,  71, v);
        v = pB[ 2 * 64 + lane]; WST4( 72,  73,  74,  75, v);
        v = pB[ 3 * 64 + lane]; WST4( 76,  77,  78,  79, v);
        v = pB[ 4 * 64 + lane]; WST4( 80,  81,  82,  83, v);
        v = pB[ 5 * 64 + lane]; WST4( 84,  85,  86,  87, v);
        v = pB[ 6 * 64 + lane]; WST4( 88,  89,  90,  91, v);
        v = pB[ 7 * 64 + lane]; WST4( 92,  93,  94,  95, v);
        v = pB[ 8 * 64 + lane]; WST4( 96,  97,  98,  99, v);
        v = pB[ 9 * 64 + lane]; WST4(100, 101, 102, 103, v);
        v = pB[10 * 64 + lane]; WST4(104, 105, 106, 107, v);
        v = pB[11 * 64 + lane]; WST4(108, 109, 110, 111, v);
        v = pB[12 * 64 + lane]; WST4(112, 113, 114, 115, v);
        v = pB[13 * 64 + lane]; WST4(116, 117, 118, 119, v);
        v = pB[14 * 64 + lane]; WST4(120, 121, 122, 123, v);
        v = pB[15 * 64 + lane]; WST4(124, 125, 126, 127, v);
    }
    const float winA0 = Win[2 * rowA], winA1 = Win[2 * rowA + 1];
    const float winB0 = Win[2 * rowB], winB1 = Win[2 * rowB + 1];

    __syncthreads();

    const float4* rv4 = reinterpret_cast<const float4*>(r_lds);
    ull* r_lds8 = reinterpret_cast<ull*>(r_lds);

    for (int t = 0; t < T_STEPS; ++t) {
        if (t > 0) {
            // Per-wave poll of the single counter: 64 lanes, same address ->
            // ONE coalesced transaction per wave per round.
            const uint32 need = (uint32)(N_WG * t);
            while (__hip_atomic_load(cnt, __ATOMIC_RELAXED, AGENT) < need)
                __builtin_amdgcn_s_sleep(1);

            // If this WG ran the rotated pred at step t-1, wave0's r_lds reads
            // must finish before staging overwrites. Workgroup-uniform branch
            // (wid/t only) => conditional __syncthreads is legal.
            if (t >= 2 && wid == ((t - 2) & 255)) __syncthreads();

            // Stage rbuf[t&1] -> LDS as 8-B relaxed loads (4/thread, r5 form).
            const ull* src8 = reinterpret_cast<const ull*>(rbuf) + (size_t)(t & 1) * (R_DIM / 2);
            #pragma unroll
            for (int j = 0; j < 4; ++j) {
                int i = tid + j * 512;
                r_lds8[i] = __hip_atomic_load(src8 + i, __ATOMIC_RELAXED, AGENT);
            }
            __syncthreads();   // barrier A: r(t) fully staged
        }

        // y = W r(t) for this wave's two rows (W in AGPRs, r broadcast from LDS).
        float4 accA = make_float4(0.f, 0.f, 0.f, 0.f);
        float4 accB = make_float4(0.f, 0.f, 0.f, 0.f);
        MV2( 0,   0,   1,   2,   3,  64,  65,  66,  67);
        MV2( 1,   4,   5,   6,   7,  68,  69,  70,  71);
        MV2( 2,   8,   9,  10,  11,  72,  73,  74,  75);
        MV2( 3,  12,  13,  14,  15,  76,  77,  78,  79);
        MV2( 4,  16,  17,  18,  19,  80,  81,  82,  83);
        MV2( 5,  20,  21,  22,  23,  84,  85,  86,  87);
        MV2( 6,  24,  25,  26,  27,  88,  89,  90,  91);
        MV2( 7,  28,  29,  30,  31,  92,  93,  94,  95);
        MV2( 8,  32,  33,  34,  35,  96,  97,  98,  99);
        MV2( 9,  36,  37,  38,  39, 100, 101, 102, 103);
        MV2(10,  40,  41,  42,  43, 104, 105, 106, 107);
        MV2(11,  44,  45,  46,  47, 108, 109, 110, 111);
        MV2(12,  48,  49,  50,  51, 112, 113, 114, 115);
        MV2(13,  52,  53,  54,  55, 116, 117, 118, 119);
        MV2(14,  56,  57,  58,  59, 120, 121, 122, 123);
        MV2(15,  60,  61,  62,  63, 124, 125, 126, 127);

        float sA = (accA.x + accA.y) + (accA.z + accA.w);
        float sB = (accB.x + accB.y) + (accB.z + accB.w);
        #pragma unroll
        for (int m = 1; m < 64; m <<= 1) {
            sA += __shfl_xor(sA, m);
            sB += __shfl_xor(sB, m);
        }

        // Publish r(t+1) rows (paired 8B atomic store). Ping-pong safe: this
        // wave saw cnt >= 256t before staging, i.e. every WG finished step t-1
        // (each add is post-drain, post-barrier-A), so r(t-1) reads are done.
        if (lane == 0) {
            float bt = b_lds[t];
            float xA = fast_tanh(sA + fmaf(winA1, bt, winA0));
            float xB = fast_tanh(sB + fmaf(winB1, bt, winB0));
            float rnA = 0.5f * (r_lds[rowA] + xA);
            float rnB = 0.5f * (r_lds[rowB] + xB);
            ull pack = ((ull)__float_as_uint(rnB) << 32) | __float_as_uint(rnA);
            ull* dst = reinterpret_cast<ull*>(rbuf)
                     + (size_t)((t + 1) & 1) * (R_DIM / 2) + (rowA >> 1);
            __hip_atomic_store(dst, pack, __ATOMIC_RELAXED, AGENT);
        }

        __syncthreads();   // barrier B: drains all waves' publish stores (vmcnt(0))
        if (tid == 0)
            (void)__hip_atomic_fetch_add(cnt, 1u, __ATOMIC_RELAXED, AGENT);

        // Rotated pred in the counter-propagation shadow (r11): WG ((t-1)&255)
        // wave0 computes out[t-1] from r_lds = r(t) after its add is issued.
        if (t >= 1 && wave == 0 && wid == ((t - 1) & 255)) {
            const float* wr = Wout + 2;
            float s = 0.0f;
            #pragma unroll
            for (int c = 0; c < K_CHUNKS; ++c) {
                int k = c * 256 + lane * 4;
                float2 wa = *reinterpret_cast<const float2*>(wr + k);
                float2 wb = *reinterpret_cast<const float2*>(wr + k + 2);
                float4 rv = rv4[c * 64 + lane];
                s = fmaf(wa.x, rv.x, s);
                s = fmaf(wa.y, rv.y, s);
                s = fmaf(wb.x, rv.z, s);
                s = fmaf(wb.y, rv.w, s);
            }
            #pragma unroll
            for (int m = 1; m < 64; m <<= 1) s += __shfl_xor(s, m);
            if (lane == 0)
                out[t - 1] = s + fmaf(Wout[1], b_lds[t - 1], Wout[0]);
        }
    }

    // Epilogue (WG0 only): out[T-1] from r(T).
    if (wid == 0) {
        const uint32 need = (uint32)(N_WG * T_STEPS);
        while (__hip_atomic_load(cnt, __ATOMIC_RELAXED, AGENT) < need)
            __builtin_amdgcn_s_sleep(1);
        __syncthreads();
        const ull* src8 = reinterpret_cast<const ull*>(rbuf) + (size_t)(T_STEPS & 1) * (R_DIM / 2);
        #pragma unroll
        for (int j = 0; j < 4; ++j) {
            int i = tid + j * 512;
            r_lds8[i] = __hip_atomic_load(src8 + i, __ATOMIC_RELAXED, AGENT);
        }
        __syncthreads();
        if (wave == 0) {
            const float* wr = Wout + 2;
            float s = 0.0f;
            #pragma unroll
            for (int c = 0; c < K_CHUNKS; ++c) {
                int k = c * 256 + lane * 4;
                float2 wa = *reinterpret_cast<const float2*>(wr + k);
                float2 wb = *reinterpret_cast<const float2*>(wr + k + 2);
                float4 rv = rv4[c * 64 + lane];
                s = fmaf(wa.x, rv.x, s);
                s = fmaf(wa.y, rv.y, s);
                s = fmaf(wb.x, rv.z, s);
                s = fmaf(wb.y, rv.w, s);
            }
            #pragma unroll
            for (int m = 1; m < 64; m <<= 1) s += __shfl_xor(s, m);
            if (lane == 0)
                out[T_STEPS - 1] = s + fmaf(Wout[1], b_lds[T_STEPS - 1], Wout[0]);
        }
    }
}

extern "C" void kernel_launch(void* const* d_in, const int* in_sizes, int n_in,
                              void* d_out, int out_size, void* d_ws, size_t ws_size,
                              hipStream_t stream) {
    (void)in_sizes; (void)n_in; (void)out_size; (void)ws_size;
    const float* batch = (const float*)d_in[0];   // (1024,1,1)
    const float* Win   = (const float*)d_in[1];   // (4096,2) row-major
    const float* W     = (const float*)d_in[2];   // (4096,4096) row-major
    const float* Wout  = (const float*)d_in[3];   // (1,4098)
    float* out  = (float*)d_out;                  // (1024,1)
    float* rbuf = (float*)d_ws;                                   // 2*4096 floats
    uint32* cnt = (uint32*)((char*)d_ws + 2 * R_DIM * sizeof(float));

    // Counter must start at 0 every launch (monotonic to 256*1024 within a run;
    // d_ws is not re-poisoned between replays).
    hipMemsetAsync(cnt, 0, sizeof(uint32), stream);

    // grid=256 WGs x 512 thr (8 waves = 2 waves/SIMD; 128 AGPR + ~100 VGPR).
    // grid == CU count => all WGs co-resident for the counter spin.
    esn_persistent<<<dim3(N_WG), dim3(N_THR), 0, stream>>>(
        batch, Win, W, Wout, out, rbuf, cnt);
}